// Round 11
// baseline (158.662 us; speedup 1.0000x reference)
//
#include <hip/hip_runtime.h>
#include <hip/hip_bf16.h>
#include <hip/hip_fp16.h>

#define IN_FT  128
#define OUT_FT 32
#define APITCH 136   // f16 pitch for A tile: 272B rows, benign b128 bank pattern

#define RPB   256    // rows per bucket (bucket = row >> 8)
#define CAP   8192   // ebin slots per bucket (mean count 4092, ~64 sigma headroom)
#define ACC_T 1024   // threads for acc
#define BIN_E 16384  // bin edges per 256-thr block (64/thread) -> ~42-edge runs

typedef _Float16 f16x8 __attribute__((ext_vector_type(8)));
typedef __attribute__((ext_vector_type(4))) float f32x4;

union H2 { unsigned u; _Float16 h[2]; };

// ---- K1 fused: blocks [0,bb)     : bin edges into fixed-cap bucket slots
//                blocks [bb,bb+gb) : sup(f16) = seq @ w via MFMA, with the
//                                    swizzled weight table built in LDS
// Bin blocks first so they start at t=0 and overlap the gemm wave.
__global__ __launch_bounds__(256) void gcn_fused(const float* __restrict__ seq,
                                                 const float* __restrict__ w,
                                                 unsigned short* __restrict__ sup,
                                                 const int* __restrict__ erow,
                                                 const int* __restrict__ ecol,
                                                 const float* __restrict__ eval,
                                                 int* __restrict__ bptr,
                                                 uint2* __restrict__ ebin,
                                                 int n, int nE, int bb) {
    __shared__ __align__(16) _Float16 at[64 * APITCH];   // 17 KB
    __shared__ __align__(16) _Float16 wl[4096];          // 8 KB swizzled weights
    __shared__ int cntS[512];
    __shared__ int curS[512];
    const int t = threadIdx.x;

    if ((int)blockIdx.x < bb) {
        // ---------------- bin branch (256 thr, 16384 edges, two-pass) --------
        cntS[t] = 0;
        cntS[t + 256] = 0;
        __syncthreads();

        const int cb = blockIdx.x * BIN_E;
        const int ce = min(cb + BIN_E, nE);

        // pass 1: bucket histogram (LDS int atomics), vectorized reads
        #pragma unroll 4
        for (int it = 0; it < 16; ++it) {
            int i0 = cb + (it * 256 + t) * 4;
            if (i0 + 4 <= ce) {
                int4 r4 = *(const int4*)&erow[i0];
                atomicAdd(&cntS[r4.x >> 8], 1);
                atomicAdd(&cntS[r4.y >> 8], 1);
                atomicAdd(&cntS[r4.z >> 8], 1);
                atomicAdd(&cntS[r4.w >> 8], 1);
            } else if (i0 < ce) {
                for (int i = i0; i < ce && i < i0 + 4; ++i)
                    atomicAdd(&cntS[erow[i] >> 8], 1);
            }
        }
        __syncthreads();

        // reserve one contiguous run per non-empty bucket
        if (cntS[t])       curS[t]       = atomicAdd(&bptr[t],       cntS[t]);
        if (cntS[t + 256]) curS[t + 256] = atomicAdd(&bptr[t + 256], cntS[t + 256]);
        __syncthreads();

        // pass 2: re-read chunk (L2-hot, <=192 KB) + place (long contiguous runs)
        #pragma unroll 2
        for (int it = 0; it < 16; ++it) {
            int i0 = cb + (it * 256 + t) * 4;
            if (i0 + 4 <= ce) {
                int4   r4 = *(const int4*)&erow[i0];
                int4   c4 = *(const int4*)&ecol[i0];
                float4 v4 = *(const float4*)&eval[i0];
                int      rr[4] = {r4.x, r4.y, r4.z, r4.w};
                unsigned cq[4];
                cq[0] = ((unsigned)c4.x << 15) | (unsigned)(v4.x * 32767.f + 0.5f);
                cq[1] = ((unsigned)c4.y << 15) | (unsigned)(v4.y * 32767.f + 0.5f);
                cq[2] = ((unsigned)c4.z << 15) | (unsigned)(v4.z * 32767.f + 0.5f);
                cq[3] = ((unsigned)c4.w << 15) | (unsigned)(v4.w * 32767.f + 0.5f);
                #pragma unroll
                for (int q = 0; q < 4; ++q) {
                    int b = rr[q] >> 8;
                    int p = atomicAdd(&curS[b], 1);
                    if (p < CAP) {               // safety clamp (never expected)
                        uint2 e;
                        e.x = cq[q];
                        e.y = (unsigned)(rr[q] & 255);
                        ebin[(size_t)b * CAP + p] = e;
                    }
                }
            } else if (i0 < ce) {
                for (int i = i0; i < ce && i < i0 + 4; ++i) {
                    int      r = erow[i];
                    unsigned q = ((unsigned)ecol[i] << 15)
                               | (unsigned)(eval[i] * 32767.f + 0.5f);
                    int b = r >> 8;
                    int p = atomicAdd(&curS[b], 1);
                    if (p < CAP) {
                        uint2 e;
                        e.x = q;
                        e.y = (unsigned)(r & 255);
                        ebin[(size_t)b * CAP + p] = e;
                    }
                }
            }
        }
        return;
    }

    // ---------------- gemm branch ----------------
    const int base = ((int)blockIdx.x - bb) * 64;

    // stage swizzled weight table into LDS (identical layout to old global wtab:
    // wl[((tile*4+kt)*64+lane)*8+j] = w[kt*32+(lane>>4)*8+j][(lane&15)+tile*16])
    for (int i = t; i < 4096; i += 256) {
        int j    = i & 7;
        int lane = (i >> 3) & 63;
        int kt   = (i >> 9) & 3;
        int tile = i >> 11;
        int k    = kt * 32 + (lane >> 4) * 8 + j;
        int c    = (lane & 15) + tile * 16;
        wl[i] = (_Float16)w[k * OUT_FT + c];
    }

    // stage A tile: 64 rows x 128 f32 -> f16, coalesced global reads
    for (int it = 0; it < 4; ++it) {
        int i     = it * 256 + t;
        int row_l = i >> 4;
        int c     = i & 15;
        int row   = base + row_l;
        f16x8 v = (f16x8)0;
        if (row < n) {
            const float4* p = (const float4*)(seq + (size_t)row * IN_FT + c * 8);
            float4 lo = p[0], hi = p[1];
            v[0] = (_Float16)lo.x; v[1] = (_Float16)lo.y;
            v[2] = (_Float16)lo.z; v[3] = (_Float16)lo.w;
            v[4] = (_Float16)hi.x; v[5] = (_Float16)hi.y;
            v[6] = (_Float16)hi.z; v[7] = (_Float16)hi.w;
        }
        *(f16x8*)&at[row_l * APITCH + c * 8] = v;
    }
    __syncthreads();

    const int wave = t >> 6;
    const int lane = t & 63;
    const int m    = lane & 15;
    const int quad = lane >> 4;

    const f16x8* wt = (const f16x8*)wl;          // contiguous b128 frag reads
    const int arow_l = wave * 16 + m;

    f32x4 acc0 = {0.f, 0.f, 0.f, 0.f};
    f32x4 acc1 = {0.f, 0.f, 0.f, 0.f};

    #pragma unroll
    for (int kt = 0; kt < 4; ++kt) {
        f16x8 a  = *(const f16x8*)&at[arow_l * APITCH + kt * 32 + quad * 8];
        f16x8 b0 = wt[(0 * 4 + kt) * 64 + lane];
        f16x8 b1 = wt[(1 * 4 + kt) * 64 + lane];
        acc0 = __builtin_amdgcn_mfma_f32_16x16x32_f16(a, b0, acc0, 0, 0, 0);
        acc1 = __builtin_amdgcn_mfma_f32_16x16x32_f16(a, b1, acc1, 0, 0, 0);
    }

    // C/D layout: col = lane&15, row = quad*4 + reg
    for (int i = 0; i < 4; ++i) {
        int ro = base + wave * 16 + quad * 4 + i;
        if (ro < n) {
            _Float16 h0 = (_Float16)acc0[i];
            _Float16 h1 = (_Float16)acc1[i];
            sup[(size_t)ro * OUT_FT + m]      = *(unsigned short*)&h0;
            sup[(size_t)ro * OUT_FT + 16 + m] = *(unsigned short*)&h1;
        }
    }
}

// ---- K2: per-bucket int-atomic row sort (LDS csr) + register-accum gather ----
// + fused relu. Block b owns rows [b*256, b*256+256).  (R6/R10 verified form)
__global__ __launch_bounds__(ACC_T) void gcn_acc(const uint2* __restrict__ ebin,
                                                 const int* __restrict__ bptr,
                                                 const unsigned* __restrict__ sup32,
                                                 float2* __restrict__ out, int n) {
    __shared__ unsigned csr[CAP];                // 32 KB row-sorted (col|val) words
    __shared__ int hist[RPB];
    __shared__ int segs[RPB];                    // inclusive scan of hist
    __shared__ int cursor[RPB];
    const int    t    = threadIdx.x;
    const int    b    = blockIdx.x;
    const int    cnt  = min(bptr[b], CAP);
    const size_t base = (size_t)b * CAP;

    if (t < RPB) hist[t] = 0;
    __syncthreads();

    // pass 1: row histogram (native ds_add_u32)
    for (int i = t; i < cnt; i += ACC_T)
        atomicAdd(&hist[ebin[base + i].y], 1);
    __syncthreads();

    // inclusive scan of 256 row counts (first 256 threads active)
    int v = 0;
    if (t < RPB) { v = hist[t]; segs[t] = v; }
    __syncthreads();
    for (int o = 1; o < RPB; o <<= 1) {
        int x = 0;
        if (t < RPB && t >= o) x = segs[t - o];
        __syncthreads();
        if (t < RPB) segs[t] += x;
        __syncthreads();
    }
    if (t < RPB) cursor[t] = segs[t] - v;        // exclusive start
    __syncthreads();

    // pass 2: place (col|val) words row-sorted into LDS (ds_add_rtn_u32 cursor)
    for (int i = t; i < cnt; i += ACC_T) {
        uint2 e = ebin[base + i];
        int   p = atomicAdd(&cursor[e.y], 1);
        csr[p] = e.x;
    }
    __syncthreads();

    // gather: 16-lane group per row, register accumulate, direct global write
    const int g = t >> 4;                        // 64 groups
    const int j = t & 15;
    const int rbase = b * RPB;
    for (int rr = g; rr < RPB; rr += ACC_T / 16) {
        int end = segs[rr];
        int st  = end - hist[rr];
        float a0 = 0.f, a1 = 0.f;
        int e = st;
        for (; e + 2 <= end; e += 2) {           // 2-edge unroll for load ILP
            unsigned c0 = csr[e], c1 = csr[e + 1];
            H2 s0; s0.u = sup32[(c0 >> 15) * 16 + j];
            H2 s1; s1.u = sup32[(c1 >> 15) * 16 + j];
            float v0 = (float)(c0 & 0x7fffu) * (1.f / 32767.f);
            float v1 = (float)(c1 & 0x7fffu) * (1.f / 32767.f);
            a0 += v0 * (float)s0.h[0] + v1 * (float)s1.h[0];
            a1 += v0 * (float)s0.h[1] + v1 * (float)s1.h[1];
        }
        if (e < end) {
            unsigned c0 = csr[e];
            H2 s0; s0.u = sup32[(c0 >> 15) * 16 + j];
            float v0 = (float)(c0 & 0x7fffu) * (1.f / 32767.f);
            a0 += v0 * (float)s0.h[0];
            a1 += v0 * (float)s0.h[1];
        }
        int row = rbase + rr;
        if (row < n) {
            float2 o;
            o.x = fmaxf(a0, 0.f);
            o.y = fmaxf(a1, 0.f);
            out[(size_t)row * 16 + j] = o;
        }
    }
}

extern "C" void kernel_launch(void* const* d_in, const int* in_sizes, int n_in,
                              void* d_out, int out_size, void* d_ws, size_t ws_size,
                              hipStream_t stream) {
    const float* seq  = (const float*)d_in[0];
    const float* w    = (const float*)d_in[1];
    const int*   erow = (const int*)d_in[2];
    const int*   ecol = (const int*)d_in[3];
    const float* eval = (const float*)d_in[4];
    float* out = (float*)d_out;

    const int n_nodes = in_sizes[0] / IN_FT;
    const int n_edges = in_sizes[2];
    const int nB      = (n_nodes + RPB - 1) / RPB;    // 391 for N=100000 (<=512)

    // workspace: sup n*32 u16 (6.4 MB) | ebin nB*CAP uint2 (25.6 MB) | bptr 512
    unsigned short* sup  = (unsigned short*)d_ws;
    uint2*          ebin = (uint2*)(sup + (size_t)n_nodes * OUT_FT);
    int*            bptr = (int*)(ebin + (size_t)nB * CAP);

    // D1: zero bucket counters (2 KB DMA fill)
    hipMemsetAsync(bptr, 0, 512 * sizeof(int), stream);

    // D2: fused bin (bb blocks, first) + gemm (gb blocks)
    int bb = (n_edges + BIN_E - 1) / BIN_E;           // 98
    int gb = (n_nodes + 63) / 64;                     // 1563
    gcn_fused<<<bb + gb, 256, 0, stream>>>(seq, w, sup, erow, ecol, eval,
                                           bptr, ebin, n_nodes, n_edges, bb);

    // D3: per-bucket int-atomic row sort + register-accumulate gather + relu
    gcn_acc<<<nB, ACC_T, 0, stream>>>(ebin, bptr, (const unsigned*)sup,
                                      (float2*)out, n_nodes);
}

// Round 12
// 152.088 us; speedup vs baseline: 1.0432x; 1.0432x over previous
//
#include <hip/hip_runtime.h>
#include <hip/hip_bf16.h>
#include <hip/hip_fp16.h>

#define IN_FT  128
#define OUT_FT 32
#define APITCH 136   // f16 pitch for A tile: 272B rows, benign b128 bank pattern

#define RPB   128    // rows per bucket (bucket = row >> 7)
#define NBMAX 1024   // bucket-counter array size (782 used)
#define CAP   4096   // ebin slots per bucket (mean 2048, ~45 sigma headroom)
#define BA_T  1024   // threads for binA
#define ACC_T 512    // threads for acc
#define BIN_E 16384  // binA edges per block (16/thread -> ~21-edge runs)

typedef _Float16 f16x8 __attribute__((ext_vector_type(8)));
typedef __attribute__((ext_vector_type(4))) float f32x4;

union H2 { unsigned u; _Float16 h[2]; };

// ---- K1: swizzled f16 weight table (8 KB) + zero bucket counters ----
// wtab[tile][kt][lane][j] = w[kt*32 + (lane>>4)*8 + j][(lane&15) + tile*16]
__global__ __launch_bounds__(256) void gcn_swz(const float* __restrict__ w,
                                               _Float16* __restrict__ wtab,
                                               int* __restrict__ bptr) {
    int t = threadIdx.x;
    bptr[t]       = 0;
    bptr[t + 256] = 0;
    bptr[t + 512] = 0;
    bptr[t + 768] = 0;
    for (int i = t; i < 2 * 4 * 64 * 8; i += 256) {
        int j    = i & 7;
        int lane = (i >> 3) & 63;
        int kt   = (i >> 9) & 3;
        int tile = i >> 11;
        int k    = kt * 32 + (lane >> 4) * 8 + j;
        int c    = (lane & 15) + tile * 16;
        wtab[i] = (_Float16)w[k * OUT_FT + c];
    }
}

// ---- K2: sup(f16) = seq @ w via MFMA with LDS-staged coalesced A ----
// (byte-identical to R10 verified form)
__global__ __launch_bounds__(256) void gcn_gemm_mfma(const float* __restrict__ seq,
                                                     const _Float16* __restrict__ wtab,
                                                     unsigned short* __restrict__ sup,
                                                     int n) {
    __shared__ __align__(16) _Float16 at[64 * APITCH];   // 17 KB
    const int t    = threadIdx.x;
    const int base = blockIdx.x * 64;

    for (int it = 0; it < 4; ++it) {
        int i     = it * 256 + t;
        int row_l = i >> 4;
        int c     = i & 15;
        int row   = base + row_l;
        f16x8 v = (f16x8)0;
        if (row < n) {
            const float4* p = (const float4*)(seq + (size_t)row * IN_FT + c * 8);
            float4 lo = p[0], hi = p[1];
            v[0] = (_Float16)lo.x; v[1] = (_Float16)lo.y;
            v[2] = (_Float16)lo.z; v[3] = (_Float16)lo.w;
            v[4] = (_Float16)hi.x; v[5] = (_Float16)hi.y;
            v[6] = (_Float16)hi.z; v[7] = (_Float16)hi.w;
        }
        *(f16x8*)&at[row_l * APITCH + c * 8] = v;
    }
    __syncthreads();

    const int wave = t >> 6;
    const int lane = t & 63;
    const int m    = lane & 15;
    const int quad = lane >> 4;

    const f16x8* wt = (const f16x8*)wtab;
    const int arow_l = wave * 16 + m;

    f32x4 acc0 = {0.f, 0.f, 0.f, 0.f};
    f32x4 acc1 = {0.f, 0.f, 0.f, 0.f};

    for (int kt = 0; kt < 4; ++kt) {
        f16x8 a  = *(const f16x8*)&at[arow_l * APITCH + kt * 32 + quad * 8];
        f16x8 b0 = wt[(0 * 4 + kt) * 64 + lane];
        f16x8 b1 = wt[(1 * 4 + kt) * 64 + lane];
        acc0 = __builtin_amdgcn_mfma_f32_16x16x32_f16(a, b0, acc0, 0, 0, 0);
        acc1 = __builtin_amdgcn_mfma_f32_16x16x32_f16(a, b1, acc1, 0, 0, 0);
    }

    // C/D layout: col = lane&15, row = quad*4 + reg
    for (int i = 0; i < 4; ++i) {
        int ro = base + wave * 16 + quad * 4 + i;
        if (ro < n) {
            _Float16 h0 = (_Float16)acc0[i];
            _Float16 h1 = (_Float16)acc1[i];
            sup[(size_t)ro * OUT_FT + m]      = *(unsigned short*)&h0;
            sup[(size_t)ro * OUT_FT + 16 + m] = *(unsigned short*)&h1;
        }
    }
}

// ---- K3: bin edges into fixed-cap bucket slots (1024 thr, 16 edges/thread) --
// bucket = row>>7 (782 buckets). ebin[b*CAP+i] = { (col<<15)|val15, row&127 }
__global__ __launch_bounds__(BA_T) void gcn_binA(const int* __restrict__ erow,
                                                 const int* __restrict__ ecol,
                                                 const float* __restrict__ eval,
                                                 int* __restrict__ bptr,
                                                 uint2* __restrict__ ebin, int nE) {
    __shared__ int cnt[NBMAX];
    __shared__ int cur[NBMAX];
    const int t  = threadIdx.x;
    const int cb = blockIdx.x * BIN_E;
    cnt[t] = 0;                                  // BA_T == NBMAX
    __syncthreads();

    int      rr[16];
    unsigned cq[16];

    // load 16 edges/thread to registers (4 x int4, coalesced) + LDS histogram
    #pragma unroll
    for (int k = 0; k < 4; ++k) {
        int i0 = cb + (k * BA_T + t) * 4;
        if (i0 + 4 <= nE) {
            int4   r4 = *(const int4*)&erow[i0];
            int4   c4 = *(const int4*)&ecol[i0];
            float4 v4 = *(const float4*)&eval[i0];
            rr[k * 4 + 0] = r4.x; rr[k * 4 + 1] = r4.y;
            rr[k * 4 + 2] = r4.z; rr[k * 4 + 3] = r4.w;
            cq[k * 4 + 0] = ((unsigned)c4.x << 15) | (unsigned)(v4.x * 32767.f + 0.5f);
            cq[k * 4 + 1] = ((unsigned)c4.y << 15) | (unsigned)(v4.y * 32767.f + 0.5f);
            cq[k * 4 + 2] = ((unsigned)c4.z << 15) | (unsigned)(v4.z * 32767.f + 0.5f);
            cq[k * 4 + 3] = ((unsigned)c4.w << 15) | (unsigned)(v4.w * 32767.f + 0.5f);
            atomicAdd(&cnt[r4.x >> 7], 1);
            atomicAdd(&cnt[r4.y >> 7], 1);
            atomicAdd(&cnt[r4.z >> 7], 1);
            atomicAdd(&cnt[r4.w >> 7], 1);
        } else {
            #pragma unroll
            for (int j = 0; j < 4; ++j) {
                int i = i0 + j;
                rr[k * 4 + j] = -1;
                if (i < nE) {
                    int r = erow[i];
                    rr[k * 4 + j] = r;
                    cq[k * 4 + j] = ((unsigned)ecol[i] << 15)
                                  | (unsigned)(eval[i] * 32767.f + 0.5f);
                    atomicAdd(&cnt[r >> 7], 1);
                }
            }
        }
    }
    __syncthreads();

    // reserve one contiguous run per non-empty bucket
    if (cnt[t]) cur[t] = atomicAdd(&bptr[t], cnt[t]);
    __syncthreads();

    // place from registers (runs land contiguously; L2 merges lines)
    #pragma unroll
    for (int k = 0; k < 16; ++k) {
        int r = rr[k];
        if (r >= 0) {
            int b = r >> 7;
            int p = atomicAdd(&cur[b], 1);
            if (p < CAP) {                       // safety clamp (never expected)
                uint2 e;
                e.x = cq[k];
                e.y = (unsigned)(r & 127);
                ebin[(size_t)b * CAP + p] = e;
            }
        }
    }
}

// ---- K4: per-bucket sort with SINGLE ebin read (LDS-staged) + gather + relu --
// Block b owns rows [b*128, b*128+128). 512 thr, 37.5 KB LDS -> 4 blocks/CU.
__global__ __launch_bounds__(ACC_T) void gcn_acc(const uint2* __restrict__ ebin,
                                                 const int* __restrict__ bptr,
                                                 const unsigned* __restrict__ sup32,
                                                 float2* __restrict__ out, int n) {
    __shared__ unsigned      cvS[CAP];           // 16 KB raw (col|val)
    __shared__ unsigned char ryS[CAP];           // 4 KB raw row
    __shared__ unsigned      csr[CAP];           // 16 KB row-sorted (col|val)
    __shared__ int hist[RPB];
    __shared__ int segs[RPB];
    __shared__ int cursor[RPB];
    const int    t    = threadIdx.x;
    const int    b    = blockIdx.x;
    const int    cnt  = min(bptr[b], CAP);
    const size_t base = (size_t)b * CAP;

    if (t < RPB) hist[t] = 0;
    __syncthreads();

    // single global pass: stage to LDS + row histogram (native ds_add_u32)
    for (int i = t; i < cnt; i += ACC_T) {
        uint2 e = ebin[base + i];
        cvS[i] = e.x;
        ryS[i] = (unsigned char)e.y;
        atomicAdd(&hist[e.y], 1);
    }
    __syncthreads();

    // inclusive scan of 128 row counts (first 128 threads active)
    int v = 0;
    if (t < RPB) { v = hist[t]; segs[t] = v; }
    __syncthreads();
    for (int o = 1; o < RPB; o <<= 1) {
        int x = 0;
        if (t < RPB && t >= o) x = segs[t - o];
        __syncthreads();
        if (t < RPB) segs[t] += x;
        __syncthreads();
    }
    if (t < RPB) cursor[t] = segs[t] - v;        // exclusive start
    __syncthreads();

    // placement from LDS (ds_add_rtn_u32 cursor; p < cnt <= CAP by construction)
    for (int i = t; i < cnt; i += ACC_T) {
        int p = atomicAdd(&cursor[ryS[i]], 1);
        csr[p] = cvS[i];
    }
    __syncthreads();

    // gather: 16-lane group per row, register accumulate, direct global write
    const int g = t >> 4;                        // 32 groups
    const int j = t & 15;
    const int rbase = b * RPB;
    for (int rr = g; rr < RPB; rr += ACC_T / 16) {
        int end = segs[rr];
        int st  = end - hist[rr];
        float a0 = 0.f, a1 = 0.f;
        int e = st;
        for (; e + 2 <= end; e += 2) {           // 2-edge unroll for load ILP
            unsigned c0 = csr[e], c1 = csr[e + 1];
            H2 s0; s0.u = sup32[(c0 >> 15) * 16 + j];
            H2 s1; s1.u = sup32[(c1 >> 15) * 16 + j];
            float v0 = (float)(c0 & 0x7fffu) * (1.f / 32767.f);
            float v1 = (float)(c1 & 0x7fffu) * (1.f / 32767.f);
            a0 += v0 * (float)s0.h[0] + v1 * (float)s1.h[0];
            a1 += v0 * (float)s0.h[1] + v1 * (float)s1.h[1];
        }
        if (e < end) {
            unsigned c0 = csr[e];
            H2 s0; s0.u = sup32[(c0 >> 15) * 16 + j];
            float v0 = (float)(c0 & 0x7fffu) * (1.f / 32767.f);
            a0 += v0 * (float)s0.h[0];
            a1 += v0 * (float)s0.h[1];
        }
        int row = rbase + rr;
        if (row < n) {
            float2 o;
            o.x = fmaxf(a0, 0.f);
            o.y = fmaxf(a1, 0.f);
            out[(size_t)row * 16 + j] = o;
        }
    }
}

extern "C" void kernel_launch(void* const* d_in, const int* in_sizes, int n_in,
                              void* d_out, int out_size, void* d_ws, size_t ws_size,
                              hipStream_t stream) {
    const float* seq  = (const float*)d_in[0];
    const float* w    = (const float*)d_in[1];
    const int*   erow = (const int*)d_in[2];
    const int*   ecol = (const int*)d_in[3];
    const float* eval = (const float*)d_in[4];
    float* out = (float*)d_out;

    const int n_nodes = in_sizes[0] / IN_FT;
    const int n_edges = in_sizes[2];
    const int nB      = (n_nodes + RPB - 1) / RPB;    // 782 for N=100000 (<=1024)

    // workspace: sup n*32 u16 (6.4 MB) | ebin nB*CAP uint2 (25.6 MB)
    //          | bptr 1024 int | wtab 4096 f16
    unsigned short* sup  = (unsigned short*)d_ws;
    uint2*          ebin = (uint2*)(sup + (size_t)n_nodes * OUT_FT);
    int*            bptr = (int*)(ebin + (size_t)nB * CAP);
    _Float16*       wtab = (_Float16*)(bptr + NBMAX);

    // K1: weight table + zero bucket counters
    gcn_swz<<<1, 256, 0, stream>>>(w, wtab, bptr);

    // K2: dense projection sup = seq @ w (f16)
    gcn_gemm_mfma<<<(n_nodes + 63) / 64, 256, 0, stream>>>(seq, wtab, sup, n_nodes);

    // K3: bucket binning (16 edges/thread, long runs)
    gcn_binA<<<(n_edges + BIN_E - 1) / BIN_E, BA_T, 0, stream>>>(erow, ecol, eval,
                                                                 bptr, ebin, n_edges);

    // K4: per-bucket single-read sort + register-accumulate gather + relu
    gcn_acc<<<nB, ACC_T, 0, stream>>>(ebin, bptr, (const unsigned*)sup,
                                      (float2*)out, n_nodes);
}